// Round 6
// baseline (219.798 us; speedup 1.0000x reference)
//
#include <hip/hip_runtime.h>
#include <hip/hip_bf16.h>

typedef __attribute__((ext_vector_type(8))) short bf16x8;
typedef __attribute__((ext_vector_type(4))) float f32x4;
typedef __attribute__((ext_vector_type(8))) unsigned short ushort8;

#define TOK   4096
#define OUTF  4096
#define INF   4096
#define KE    4160   // 4096 + 16 lora + 48 zero pad = 65 K-tiles of 64
#define NKT   65
#define RANKD 16

#define VMCNT(n) asm volatile("s_waitcnt vmcnt(" #n ")" ::: "memory")
#define LGKM(n)  asm volatile("s_waitcnt lgkmcnt(" #n ")" ::: "memory")
#define SCHED0   __builtin_amdgcn_sched_barrier(0)
#define BAR      __builtin_amdgcn_s_barrier()

static __device__ __forceinline__ unsigned short f2b(float f) {
  __hip_bfloat16 b = __float2bfloat16(f);
  return __builtin_bit_cast(unsigned short, b);
}

static __device__ __forceinline__ void gload_lds16(const void* g, void* l) {
  __builtin_amdgcn_global_load_lds(
      (const __attribute__((address_space(1))) void*)g,
      (__attribute__((address_space(3))) void*)l, 16, 0, 0);
}

// ---- kernel 1: fused x->bf16 conversion + LoRA xA, writes all of Xe ----
__global__ __launch_bounds__(256) void k_xa(const float* __restrict__ x,
                                            const float* __restrict__ A,
                                            unsigned short* __restrict__ Xe) {
  const int lane = threadIdx.x & 63;
  const int wave = threadIdx.x >> 6;
  const int m0 = blockIdx.x * 16 + wave * 4;
  float p[4][16];
#pragma unroll
  for (int a = 0; a < 4; ++a)
#pragma unroll
    for (int r = 0; r < 16; ++r) p[a][r] = 0.f;

#pragma unroll 2
  for (int it = 0; it < 16; ++it) {
    const int k = it * 256 + lane * 4;
    float av[4][16];
#pragma unroll
    for (int j = 0; j < 4; ++j)
#pragma unroll
      for (int g = 0; g < 4; ++g)
        *(float4*)&av[j][g * 4] = *(const float4*)&A[(size_t)(k + j) * RANKD + g * 4];
#pragma unroll
    for (int rr = 0; rr < 4; ++rr) {
      const float4 xv = *(const float4*)&x[(size_t)(m0 + rr) * INF + k];
      ushort4 w;
      w.x = f2b(xv.x); w.y = f2b(xv.y); w.z = f2b(xv.z); w.w = f2b(xv.w);
      *(ushort4*)&Xe[(size_t)(m0 + rr) * KE + k] = w;
#pragma unroll
      for (int r = 0; r < 16; ++r)
        p[rr][r] += xv.x * av[0][r] + xv.y * av[1][r] + xv.z * av[2][r] + xv.w * av[3][r];
    }
  }
#pragma unroll
  for (int rr = 0; rr < 4; ++rr)
#pragma unroll
    for (int r = 0; r < 16; ++r) {
      float v = p[rr][r];
      v += __shfl_xor(v, 1);
      v += __shfl_xor(v, 2);
      v += __shfl_xor(v, 4);
      v += __shfl_xor(v, 8);
      v += __shfl_xor(v, 16);
      v += __shfl_xor(v, 32);
      p[rr][r] = v;
    }
  const ushort8 z = {0, 0, 0, 0, 0, 0, 0, 0};
#pragma unroll
  for (int rr = 0; rr < 4; ++rr) {
    unsigned short* dst = Xe + (size_t)(m0 + rr) * KE + INF;
    if (lane == 0) {
      ushort8 v0, v1;
#pragma unroll
      for (int r = 0; r < 8; ++r) v0[r] = f2b(2.f * p[rr][r]);
#pragma unroll
      for (int r = 0; r < 8; ++r) v1[r] = f2b(2.f * p[rr][8 + r]);
      *(ushort8*)(dst + 0) = v0;
      *(ushort8*)(dst + 8) = v1;
    }
    if (lane < 6) *(ushort8*)(dst + 16 + lane * 8) = z;
  }
}

// ---- kernel 2: We fill (dequant + B lora cols + pad) ----
__global__ __launch_bounds__(256) void k_we(const int* __restrict__ q,
                                            const float* __restrict__ absmax,
                                            const float* __restrict__ cb,
                                            const float* __restrict__ B,
                                            unsigned short* __restrict__ We) {
  __shared__ float cbs[16];
  if (threadIdx.x < 16) cbs[threadIdx.x] = cb[threadIdx.x];
  __syncthreads();
  const int lane = threadIdx.x & 63;
  const int wave = threadIdx.x >> 6;
  const int o = blockIdx.x * 4 + wave;
#pragma unroll
  for (int it = 0; it < 8; ++it) {
    const int k0 = it * 512 + lane * 8;
    const int4 q0 = *(const int4*)&q[(size_t)o * INF + k0];
    const int4 q1 = *(const int4*)&q[(size_t)o * INF + k0 + 4];
    const float am = absmax[(size_t)o * 64 + (k0 >> 6)];
    ushort8 w;
    w[0] = f2b(cbs[q0.x] * am); w[1] = f2b(cbs[q0.y] * am);
    w[2] = f2b(cbs[q0.z] * am); w[3] = f2b(cbs[q0.w] * am);
    w[4] = f2b(cbs[q1.x] * am); w[5] = f2b(cbs[q1.y] * am);
    w[6] = f2b(cbs[q1.z] * am); w[7] = f2b(cbs[q1.w] * am);
    *(ushort8*)&We[(size_t)o * KE + k0] = w;
  }
  unsigned short* dst = We + (size_t)o * KE + INF;
  dst[lane] = (lane < 16) ? f2b(B[(size_t)lane * OUTF + o]) : (unsigned short)0;
}

// ---- GEMM helpers ----
template <int M0, int N0>
static __device__ __forceinline__ void quad(f32x4 (&acc)[8][4],
                                            const bf16x8 (&AF)[4][2],
                                            const bf16x8 (&BF)[2][2]) {
  __builtin_amdgcn_s_setprio(1);
#pragma unroll
  for (int m = 0; m < 4; ++m)
#pragma unroll
    for (int n = 0; n < 2; ++n)
#pragma unroll
      for (int ks = 0; ks < 2; ++ks)
        acc[M0 + m][N0 + n] = __builtin_amdgcn_mfma_f32_16x16x32_bf16(
            AF[m][ks], BF[n][ks], acc[M0 + m][N0 + n], 0, 0, 0);
  __builtin_amdgcn_s_setprio(0);
}

template <int BUF, int M0>
static __device__ __forceinline__ void rdA(bf16x8 (&AF)[4][2], const char* LB,
                                           int aRow, const int (&aK)[2]) {
#pragma unroll
  for (int m = 0; m < 4; ++m)
#pragma unroll
    for (int ks = 0; ks < 2; ++ks)
      AF[m][ks] = *(const bf16x8*)(LB + BUF * 65536 + aRow + (M0 + m) * 2048 + aK[ks]);
}

template <int BUF, int N0>
static __device__ __forceinline__ void rdB(bf16x8 (&BF)[2][2], const char* LB,
                                           int bRow, const int (&aK)[2]) {
#pragma unroll
  for (int n = 0; n < 2; ++n)
#pragma unroll
    for (int ks = 0; ks < 2; ++ks)
      BF[n][ks] = *(const bf16x8*)(LB + BUF * 65536 + bRow + (N0 + n) * 2048 + aK[ks]);
}

// stage one half-tile (128 rows; this wave's 16-row share): 2 x gload_lds16
template <int BUF, int REGION, int H>
static __device__ __forceinline__ void stageHT(int t, const unsigned short* p0,
                                               const unsigned short* p1,
                                               unsigned short* LDS, int w1024) {
  unsigned short* d = LDS + BUF * 32768 + REGION * 16384 + H * 8192 + w1024;
  gload_lds16(p0 + (size_t)t * 64, d);
  gload_lds16(p1 + (size_t)t * 64, d + 512);
}

// ---------------- kernel 3: out = Xe @ We^T + bias ----------------
// 256x256 tile, BK=64, 8 waves (2Mx4N), 2-buf LDS (128 KB), 8-phase schedule.
// Stage slots re-derived so each buf region is staged only AFTER the barrier
// that follows all waves' completed reads of it (r5 raced B-lo vs ph3's bHi):
//   buf0-A done ph2-end -> stage ph3/ph4; buf0-B done ph3-end -> stage ph4/ph5;
//   buf1-A done ph6-end -> stage ph7/ph8; buf1-B done ph7-end -> stage ph8/ph1'.
// vmcnt(6) at ph4 (tile t0+1 landed) and ph8 (tile t0+2 landed) only.
__global__ __launch_bounds__(512, 2) void k_gemm(const unsigned short* __restrict__ Xe,
                                                 const unsigned short* __restrict__ We,
                                                 const float* __restrict__ bias,
                                                 float* __restrict__ out) {
  extern __shared__ unsigned short LDS[];   // 2 bufs x (A 32KB + B 32KB) = 128 KB
  const char* LB = (const char*)LDS;

  const int tid  = threadIdx.x;
  const int lane = tid & 63;
  const int wave = tid >> 6;        // 0..7
  const int waveM = wave >> 2;      // 0..1
  const int waveN = wave & 3;       // 0..3

  // XCD chunking: 256 wgs, 32 per XCD as 4 tile-rows x 8 tile-cols (bijective)
  const int wg   = blockIdx.x;
  const int xcd  = wg & 7;
  const int loc  = wg >> 3;
  const int trB  = ((xcd & 3) * 4 + (loc >> 3)) * 256;
  const int tcB  = ((xcd >> 2) * 8 + (loc & 7)) * 256;

  // ---- staging source pointers (pre-swizzled global, linear LDS dest) ----
  const int r8 = lane >> 3;                                   // 0..7
  const int srcsw = ((lane & 7) * 8) ^ ((r8 & 7) << 3);       // ushort offset in row
  const unsigned short* pA[2][2];
  const unsigned short* pB[2][2];
#pragma unroll
  for (int h = 0; h < 2; ++h)
#pragma unroll
    for (int j = 0; j < 2; ++j) {
      pA[h][j] = Xe + (size_t)(trB + h * 128 + wave * 16 + j * 8 + r8) * KE + srcsw;
      pB[h][j] = We + (size_t)(tcB + h * 128 + wave * 16 + j * 8 + r8) * KE + srcsw;
    }
  const int w1024 = wave * 1024;   // dest ushort offset of this wave's 16-row share

  // ---- fragment-read constants (swizzled byte offsets, 128B rows) ----
  const int fr = lane & 15;
  const int aRow = (waveM * 128 + fr) * 128;            // byte, A region
  const int bRow = 32768 + (waveN * 64 + fr) * 128;     // byte, B region
  const int s = (fr & 7) << 4;
  const int cL = (lane >> 4) * 16;
  const int aK[2] = {cL ^ s, (64 + cL) ^ s};

  f32x4 acc[8][4];
#pragma unroll
  for (int i = 0; i < 8; ++i)
#pragma unroll
    for (int j = 0; j < 4; ++j) acc[i][j] = f32x4{0.f, 0.f, 0.f, 0.f};

#define ST_A(buf_, h_, t_) stageHT<buf_, 0, h_>((t_), pA[h_][0], pA[h_][1], LDS, w1024)
#define ST_B(buf_, h_, t_) stageHT<buf_, 1, h_>((t_), pB[h_][0], pB[h_][1], LDS, w1024)

  // prologue: tile0 (buf0) fully + tile1 (buf1) minus Bhi; wait tile0
  ST_A(0, 0, 0); ST_A(0, 1, 0); ST_B(0, 0, 0); ST_B(0, 1, 0);
  ST_A(1, 0, 1); ST_A(1, 1, 1); ST_B(1, 0, 1);
  VMCNT(6);
  BAR; SCHED0;

  bf16x8 aLo[4][2], aHi[4][2], bLo[2][2], bHi[2][2];

  for (int i = 0; i < 32; ++i) {
    const int t0 = 2 * i;
    // ---- ph1: read Alo,Blo(t0,buf0); stage Bhi(t0+1 -> buf1) [buf1-B free since prev ph7-end] ----
    rdA<0, 0>(aLo, LB, aRow, aK);
    rdB<0, 0>(bLo, LB, bRow, aK);
    ST_B(1, 1, t0 + 1);
    LGKM(8);
    BAR; LGKM(0); SCHED0;
    quad<0, 0>(acc, aLo, bLo);
    BAR; SCHED0;
    // ---- ph2: read Ahi(t0); no stage ----
    rdA<0, 4>(aHi, LB, aRow, aK);
    BAR; LGKM(0); SCHED0;
    quad<4, 0>(acc, aHi, bLo);
    BAR; SCHED0;
    // ---- ph3: read Bhi(t0); stage Alo(t0+2) [buf0-A reads done ph2-end] ----
    rdB<0, 2>(bHi, LB, bRow, aK);
    ST_A(0, 0, t0 + 2);
    BAR; LGKM(0); SCHED0;
    quad<0, 2>(acc, aLo, bHi);
    BAR; SCHED0;
    // ---- ph4: stage Ahi+Blo(t0+2) [buf0-B reads done ph3-end]; vmcnt(6) -> tile t0+1 landed ----
    ST_A(0, 1, t0 + 2);
    ST_B(0, 0, t0 + 2);
    BAR; SCHED0;
    quad<4, 2>(acc, aHi, bHi);
    VMCNT(6);
    BAR; SCHED0;
    // ---- ph5: read Alo,Blo(t0+1,buf1); stage Bhi(t0+2) ----
    rdA<1, 0>(aLo, LB, aRow, aK);
    rdB<1, 0>(bLo, LB, bRow, aK);
    ST_B(0, 1, t0 + 2);
    LGKM(8);
    BAR; LGKM(0); SCHED0;
    quad<0, 0>(acc, aLo, bLo);
    BAR; SCHED0;
    // ---- ph6: read Ahi(t0+1); no stage ----
    rdA<1, 4>(aHi, LB, aRow, aK);
    BAR; LGKM(0); SCHED0;
    quad<4, 0>(acc, aHi, bLo);
    BAR; SCHED0;
    // ---- ph7: read Bhi(t0+1); stage Alo(t0+3) [buf1-A reads done ph6-end] ----
    rdB<1, 2>(bHi, LB, bRow, aK);
    if (i < 31) ST_A(1, 0, t0 + 3);
    BAR; LGKM(0); SCHED0;
    quad<0, 2>(acc, aLo, bHi);
    BAR; SCHED0;
    // ---- ph8: stage Ahi+Blo(t0+3) [buf1-B reads done ph7-end]; vmcnt(6) -> tile t0+2 landed ----
    if (i < 31) { ST_A(1, 1, t0 + 3); ST_B(1, 0, t0 + 3); }
    BAR; SCHED0;
    quad<4, 2>(acc, aHi, bHi);
    VMCNT(6);
    BAR; SCHED0;
  }

  // ---- peel tile 64 (buf0) ----
  VMCNT(0);
  BAR; SCHED0;
  rdA<0, 0>(aLo, LB, aRow, aK);
  rdA<0, 4>(aHi, LB, aRow, aK);
  rdB<0, 0>(bLo, LB, bRow, aK);
  rdB<0, 2>(bHi, LB, bRow, aK);
  LGKM(0); SCHED0;
  quad<0, 0>(acc, aLo, bLo);
  quad<4, 0>(acc, aHi, bLo);
  quad<0, 2>(acc, aLo, bHi);
  quad<4, 2>(acc, aHi, bHi);
#undef ST_A
#undef ST_B

  // epilogue: C/D layout col = lane&15, row = (lane>>4)*4 + reg
  const int rq = (lane >> 4) * 4;
#pragma unroll
  for (int j = 0; j < 4; ++j) {
    const int n = tcB + waveN * 64 + j * 16 + fr;
    const float bsv = bias[n];
#pragma unroll
    for (int i = 0; i < 8; ++i) {
      const int m = trB + waveM * 128 + i * 16 + rq;
#pragma unroll
      for (int e = 0; e < 4; ++e)
        out[(size_t)(m + e) * OUTF + n] = acc[i][j][e] + bsv;
    }
  }
}

extern "C" void kernel_launch(void* const* d_in, const int* in_sizes, int n_in,
                              void* d_out, int out_size, void* d_ws, size_t ws_size,
                              hipStream_t stream) {
  const float* x      = (const float*)d_in[0];
  const int*   q      = (const int*)d_in[1];
  const float* absmax = (const float*)d_in[2];
  const float* cb     = (const float*)d_in[3];
  const float* bias   = (const float*)d_in[4];
  const float* A      = (const float*)d_in[5];
  const float* B      = (const float*)d_in[6];
  float* out = (float*)d_out;

  unsigned short* Xe = (unsigned short*)d_ws;              // 4096*4160*2 B
  unsigned short* We = Xe + (size_t)TOK * KE;              // 4096*4160*2 B

  hipFuncSetAttribute((const void*)k_gemm,
                      hipFuncAttributeMaxDynamicSharedMemorySize, 131072);

  k_xa<<<TOK / 16, 256, 0, stream>>>(x, A, Xe);
  k_we<<<OUTF / 4, 256, 0, stream>>>(q, absmax, cb, B, We);
  k_gemm<<<256, 512, 131072, stream>>>(Xe, We, bias, out);
}

// Round 7
// 211.391 us; speedup vs baseline: 1.0398x; 1.0398x over previous
//
#include <hip/hip_runtime.h>
#include <hip/hip_bf16.h>

typedef __attribute__((ext_vector_type(8))) short bf16x8;
typedef __attribute__((ext_vector_type(4))) float f32x4;
typedef __attribute__((ext_vector_type(8))) unsigned short ushort8;

#define TOK   4096
#define OUTF  4096
#define INF   4096
#define KE    4160   // 4096 + 16 lora + 48 zero pad -> 130 K-tiles of 32
#define NT    130    // KE / 32
#define RANKD 16

static __device__ __forceinline__ unsigned short f2b(float f) {
  __hip_bfloat16 b = __float2bfloat16(f);
  return __builtin_bit_cast(unsigned short, b);
}

static __device__ __forceinline__ void gload_lds16(const void* g, void* l) {
  __builtin_amdgcn_global_load_lds(
      (const __attribute__((address_space(1))) void*)g,
      (__attribute__((address_space(3))) void*)l, 16, 0, 0);
}

// ---- kernel 1 (fused prep): blocks 0..511 fill Xe (bf16 x + lora cols via
// on-the-fly x@A); blocks 512..1535 fill We (NF4 dequant + B cols + pad).
// The two halves write disjoint buffers and run concurrently across CUs.
__global__ __launch_bounds__(256) void k_prep(const float* __restrict__ x,
                                              const float* __restrict__ A,
                                              const int* __restrict__ q,
                                              const float* __restrict__ absmax,
                                              const float* __restrict__ cb,
                                              const float* __restrict__ B,
                                              unsigned short* __restrict__ Xe,
                                              unsigned short* __restrict__ We) {
  const int lane = threadIdx.x & 63;
  const int wave = threadIdx.x >> 6;
  const int bid  = blockIdx.x;

  if (bid < 512) {
    // ---------- Xe fill: 8 rows/block, 2 rows/wave (2 waves/SIMD TLP) ----------
    const int m0 = bid * 8 + wave * 2;
    float p[2][16];
#pragma unroll
    for (int a = 0; a < 2; ++a)
#pragma unroll
      for (int r = 0; r < 16; ++r) p[a][r] = 0.f;

#pragma unroll 2
    for (int it = 0; it < 16; ++it) {
      const int k = it * 256 + lane * 4;
      float av[4][16];
#pragma unroll
      for (int j = 0; j < 4; ++j)
#pragma unroll
        for (int g = 0; g < 4; ++g)
          *(float4*)&av[j][g * 4] = *(const float4*)&A[(size_t)(k + j) * RANKD + g * 4];
#pragma unroll
      for (int rr = 0; rr < 2; ++rr) {
        const float4 xv = *(const float4*)&x[(size_t)(m0 + rr) * INF + k];
        ushort4 w;
        w.x = f2b(xv.x); w.y = f2b(xv.y); w.z = f2b(xv.z); w.w = f2b(xv.w);
        *(ushort4*)&Xe[(size_t)(m0 + rr) * KE + k] = w;
#pragma unroll
        for (int r = 0; r < 16; ++r)
          p[rr][r] += xv.x * av[0][r] + xv.y * av[1][r] + xv.z * av[2][r] + xv.w * av[3][r];
      }
    }
#pragma unroll
    for (int rr = 0; rr < 2; ++rr)
#pragma unroll
      for (int r = 0; r < 16; ++r) {
        float v = p[rr][r];
        v += __shfl_xor(v, 1);
        v += __shfl_xor(v, 2);
        v += __shfl_xor(v, 4);
        v += __shfl_xor(v, 8);
        v += __shfl_xor(v, 16);
        v += __shfl_xor(v, 32);
        p[rr][r] = v;
      }
    const ushort8 z = {0, 0, 0, 0, 0, 0, 0, 0};
#pragma unroll
    for (int rr = 0; rr < 2; ++rr) {
      unsigned short* dst = Xe + (size_t)(m0 + rr) * KE + INF;
      if (lane == 0) {
        ushort8 v0, v1;
#pragma unroll
        for (int r = 0; r < 8; ++r) v0[r] = f2b(2.f * p[rr][r]);
#pragma unroll
        for (int r = 0; r < 8; ++r) v1[r] = f2b(2.f * p[rr][8 + r]);
        *(ushort8*)(dst + 0) = v0;
        *(ushort8*)(dst + 8) = v1;
      }
      if (lane < 6) *(ushort8*)(dst + 16 + lane * 8) = z;   // pad 4112..4159
    }
  } else {
    // ---------- We fill: 4 rows/block ----------
    __shared__ float cbs[16];
    if (threadIdx.x < 16) cbs[threadIdx.x] = cb[threadIdx.x];
    __syncthreads();
    const int o = (bid - 512) * 4 + wave;
#pragma unroll
    for (int it = 0; it < 8; ++it) {
      const int k0 = it * 512 + lane * 8;
      const int4 q0 = *(const int4*)&q[(size_t)o * INF + k0];
      const int4 q1 = *(const int4*)&q[(size_t)o * INF + k0 + 4];
      const float am = absmax[(size_t)o * 64 + (k0 >> 6)];
      ushort8 w;
      w[0] = f2b(cbs[q0.x] * am); w[1] = f2b(cbs[q0.y] * am);
      w[2] = f2b(cbs[q0.z] * am); w[3] = f2b(cbs[q0.w] * am);
      w[4] = f2b(cbs[q1.x] * am); w[5] = f2b(cbs[q1.y] * am);
      w[6] = f2b(cbs[q1.z] * am); w[7] = f2b(cbs[q1.w] * am);
      *(ushort8*)&We[(size_t)o * KE + k0] = w;
    }
    unsigned short* dst = We + (size_t)o * KE + INF;
    dst[lane] = (lane < 16) ? f2b(B[(size_t)lane * OUTF + o]) : (unsigned short)0;
  }
}

// ---------------- kernel 2: out = Xe @ We^T + bias  (r4 structure, verbatim) ----
// 256x256 tile, BK=32, 8 waves (2Mx4N), 4-deep LDS ring (128 KB).
// Derived-waits pipeline: per K-tile one vmcnt(4)+barrier; two 16-MFMA setprio
// clusters; ds_reads pipelined one phase ahead (no lgkmcnt(0) drains).
__global__ __launch_bounds__(512, 2) void k_gemm(const unsigned short* __restrict__ Xe,
                                                 const unsigned short* __restrict__ We,
                                                 const float* __restrict__ bias,
                                                 float* __restrict__ out) {
  extern __shared__ unsigned short LDS[];   // 4 bufs x (A 8KB + B 8KB) = 128 KB

  const int tid  = threadIdx.x;
  const int lane = tid & 63;
  const int wave = tid >> 6;        // 0..7
  const int waveM = wave >> 2;      // 0..1 -> rows [waveM*128, +128)
  const int waveN = wave & 3;       // 0..3 -> cols [waveN*64, +64)

  // XCD chunking: 256 wgs, 32 per XCD as 4 tile-rows x 8 tile-cols (bijective)
  const int wg   = blockIdx.x;
  const int xcd  = wg & 7;
  const int loc  = wg >> 3;                 // 0..31
  const int trB  = ((xcd & 3) * 4 + (loc >> 3)) * 256;
  const int tcB  = ((xcd >> 2) * 8 + (loc & 7)) * 256;

  // ---- staging constants (linear LDS dest, pre-swizzled global source) ----
  const int srow = lane >> 2;
  const int wpr  = ((lane & 3) * 8) ^ (((lane >> 3) & 3) << 3); // ushort offset
  const unsigned short* gA0 = Xe + (size_t)(trB +       wave * 16 + srow) * KE + wpr;
  const unsigned short* gA1 = Xe + (size_t)(trB + 128 + wave * 16 + srow) * KE + wpr;
  const unsigned short* gB0 = We + (size_t)(tcB +       wave * 16 + srow) * KE + wpr;
  const unsigned short* gB1 = We + (size_t)(tcB + 128 + wave * 16 + srow) * KE + wpr;
  const int dA0 = wave * 512;
  const int dA1 = 4096 + wave * 512;
  const int dB0 = 8192 + wave * 512;
  const int dB1 = 12288 + wave * 512;

  // ---- fragment-read constants (swizzled byte offsets) ----
  const int fr  = lane & 15;
  const int cbk = (lane >> 4) * 16;
  const int sw  = ((fr >> 1) & 3) << 4;
  const int aoff = (waveM * 128 + fr) * 64 + (cbk ^ sw);
  const int boff = 16384 + (waveN * 64 + fr) * 64 + (cbk ^ sw);

  f32x4 acc[8][4];
#pragma unroll
  for (int i = 0; i < 8; ++i)
#pragma unroll
    for (int j = 0; j < 4; ++j) acc[i][j] = f32x4{0.f, 0.f, 0.f, 0.f};

#define STAGE(t)                                                        \
  {                                                                     \
    const int sb_ = ((t) & 3) * 16384;                                  \
    const int k0_ = (t) * 32;                                           \
    gload_lds16(gA0 + k0_, LDS + sb_ + dA0);                            \
    gload_lds16(gA1 + k0_, LDS + sb_ + dA1);                            \
    gload_lds16(gB0 + k0_, LDS + sb_ + dB0);                            \
    gload_lds16(gB1 + k0_, LDS + sb_ + dB1);                            \
  }

  // prologue: stage tiles 0,1; wait tile 0; pre-read tile 0's first-phase frags
  STAGE(0)
  STAGE(1)
  asm volatile("s_waitcnt vmcnt(4)" ::: "memory");
  __builtin_amdgcn_s_barrier();
  __builtin_amdgcn_sched_barrier(0);

  bf16x8 aLo[4], aHi[4], b[4], aLoN[4], bN[4];
  {
    const char* base0 = (const char*)LDS;
#pragma unroll
    for (int i = 0; i < 4; ++i)
      aLo[i] = *(const bf16x8*)(base0 + aoff + i * 1024);
#pragma unroll
    for (int j = 0; j < 4; ++j)
      b[j] = *(const bf16x8*)(base0 + boff + j * 1024);
  }

  for (int T = 0; T < NT - 2; ++T) {
    const char* base  = (const char*)LDS + (T & 3) * 32768;
    const char* baseN = (const char*)LDS + ((T + 1) & 3) * 32768;

    // ---- P0: read a4-7(T); stage T+2; MFMA lo; vmcnt(4)+barrier ----
#pragma unroll
    for (int i = 0; i < 4; ++i)
      aHi[i] = *(const bf16x8*)(base + aoff + (4 + i) * 1024);
    STAGE(T + 2)
    __builtin_amdgcn_s_setprio(1);
#pragma unroll
    for (int i = 0; i < 4; ++i)
#pragma unroll
      for (int j = 0; j < 4; ++j)
        acc[i][j] = __builtin_amdgcn_mfma_f32_16x16x32_bf16(aLo[i], b[j], acc[i][j], 0, 0, 0);
    __builtin_amdgcn_s_setprio(0);
    asm volatile("s_waitcnt vmcnt(4)" ::: "memory");   // tile T+1 landed; T+2 in flight
    __builtin_amdgcn_s_barrier();
    __builtin_amdgcn_sched_barrier(0);

    // ---- P1: read a0-3,b0-3(T+1); MFMA hi ----
#pragma unroll
    for (int i = 0; i < 4; ++i)
      aLoN[i] = *(const bf16x8*)(baseN + aoff + i * 1024);
#pragma unroll
    for (int j = 0; j < 4; ++j)
      bN[j] = *(const bf16x8*)(baseN + boff + j * 1024);
    __builtin_amdgcn_s_setprio(1);
#pragma unroll
    for (int i = 0; i < 4; ++i)
#pragma unroll
      for (int j = 0; j < 4; ++j)
        acc[4 + i][j] = __builtin_amdgcn_mfma_f32_16x16x32_bf16(aHi[i], b[j], acc[4 + i][j], 0, 0, 0);
    __builtin_amdgcn_s_setprio(0);
#pragma unroll
    for (int i = 0; i < 4; ++i) aLo[i] = aLoN[i];
#pragma unroll
    for (int j = 0; j < 4; ++j) b[j] = bN[j];
  }

  // ---- peel T = NT-2: no stage; vmcnt(0) so tile NT-1 lands ----
  {
    const int T = NT - 2;
    const char* base  = (const char*)LDS + (T & 3) * 32768;
    const char* baseN = (const char*)LDS + ((T + 1) & 3) * 32768;
#pragma unroll
    for (int i = 0; i < 4; ++i)
      aHi[i] = *(const bf16x8*)(base + aoff + (4 + i) * 1024);
#pragma unroll
    for (int i = 0; i < 4; ++i)
#pragma unroll
      for (int j = 0; j < 4; ++j)
        acc[i][j] = __builtin_amdgcn_mfma_f32_16x16x32_bf16(aLo[i], b[j], acc[i][j], 0, 0, 0);
    asm volatile("s_waitcnt vmcnt(0)" ::: "memory");
    __builtin_amdgcn_s_barrier();
    __builtin_amdgcn_sched_barrier(0);
#pragma unroll
    for (int i = 0; i < 4; ++i)
      aLoN[i] = *(const bf16x8*)(baseN + aoff + i * 1024);
#pragma unroll
    for (int j = 0; j < 4; ++j)
      bN[j] = *(const bf16x8*)(baseN + boff + j * 1024);
#pragma unroll
    for (int i = 0; i < 4; ++i)
#pragma unroll
      for (int j = 0; j < 4; ++j)
        acc[4 + i][j] = __builtin_amdgcn_mfma_f32_16x16x32_bf16(aHi[i], b[j], acc[4 + i][j], 0, 0, 0);
#pragma unroll
    for (int i = 0; i < 4; ++i) aLo[i] = aLoN[i];
#pragma unroll
    for (int j = 0; j < 4; ++j) b[j] = bN[j];
  }
  // ---- peel T = NT-1: last tile, no next reads ----
  {
    const int T = NT - 1;
    const char* base = (const char*)LDS + (T & 3) * 32768;
#pragma unroll
    for (int i = 0; i < 4; ++i)
      aHi[i] = *(const bf16x8*)(base + aoff + (4 + i) * 1024);
#pragma unroll
    for (int i = 0; i < 4; ++i)
#pragma unroll
      for (int j = 0; j < 4; ++j)
        acc[i][j] = __builtin_amdgcn_mfma_f32_16x16x32_bf16(aLo[i], b[j], acc[i][j], 0, 0, 0);
#pragma unroll
    for (int i = 0; i < 4; ++i)
#pragma unroll
      for (int j = 0; j < 4; ++j)
        acc[4 + i][j] = __builtin_amdgcn_mfma_f32_16x16x32_bf16(aHi[i], b[j], acc[4 + i][j], 0, 0, 0);
  }
#undef STAGE

  // epilogue: C/D layout col = lane&15, row = (lane>>4)*4 + reg
  const int rq = (lane >> 4) * 4;
#pragma unroll
  for (int j = 0; j < 4; ++j) {
    const int n = tcB + waveN * 64 + j * 16 + fr;
    const float bsv = bias[n];
#pragma unroll
    for (int i = 0; i < 8; ++i) {
      const int m = trB + waveM * 128 + i * 16 + rq;
#pragma unroll
      for (int e = 0; e < 4; ++e)
        out[(size_t)(m + e) * OUTF + n] = acc[i][j][e] + bsv;
    }
  }
}

extern "C" void kernel_launch(void* const* d_in, const int* in_sizes, int n_in,
                              void* d_out, int out_size, void* d_ws, size_t ws_size,
                              hipStream_t stream) {
  const float* x      = (const float*)d_in[0];
  const int*   q      = (const int*)d_in[1];
  const float* absmax = (const float*)d_in[2];
  const float* cb     = (const float*)d_in[3];
  const float* bias   = (const float*)d_in[4];
  const float* A      = (const float*)d_in[5];
  const float* B      = (const float*)d_in[6];
  float* out = (float*)d_out;

  unsigned short* Xe = (unsigned short*)d_ws;              // 4096*4160*2 B
  unsigned short* We = Xe + (size_t)TOK * KE;              // 4096*4160*2 B

  hipFuncSetAttribute((const void*)k_gemm,
                      hipFuncAttributeMaxDynamicSharedMemorySize, 131072);

  k_prep<<<1536, 256, 0, stream>>>(x, A, q, absmax, cb, B, Xe, We);
  k_gemm<<<256, 512, 131072, stream>>>(Xe, We, bias, out);
}

// Round 8
// 192.567 us; speedup vs baseline: 1.1414x; 1.0978x over previous
//
#include <hip/hip_runtime.h>
#include <hip/hip_bf16.h>

typedef __attribute__((ext_vector_type(8))) short bf16x8;
typedef __attribute__((ext_vector_type(4))) float f32x4;
typedef __attribute__((ext_vector_type(8))) unsigned short ushort8;

#define TOK   4096
#define OUTF  4096
#define INF   4096
#define KE    4160   // 4096 + 16 lora + 48 zero pad -> 130 K-tiles of 32
#define NT    130    // KE / 32
#define RANKD 16

static __device__ __forceinline__ unsigned short f2b(float f) {
  __hip_bfloat16 b = __float2bfloat16(f);
  return __builtin_bit_cast(unsigned short, b);
}

static __device__ __forceinline__ void gload_lds16(const void* g, void* l) {
  __builtin_amdgcn_global_load_lds(
      (const __attribute__((address_space(1))) void*)g,
      (__attribute__((address_space(3))) void*)l, 16, 0, 0);
}

// ---- kernel 1 (prep, 3 concurrent segments):
//   blocks    0..255 : xA = x@A (r1 pattern, 4 rows/wave) -> Xe lora cols + pad
//   blocks 256..1279 : Xe[:,0:4096] = bf16(x)  (pure streaming)
//   blocks 1280..2303: We = NF4 dequant + B lora cols + pad
__global__ __launch_bounds__(256) void k_prep(const float* __restrict__ x,
                                              const float* __restrict__ A,
                                              const int* __restrict__ q,
                                              const float* __restrict__ absmax,
                                              const float* __restrict__ cb,
                                              const float* __restrict__ B,
                                              unsigned short* __restrict__ Xe,
                                              unsigned short* __restrict__ We) {
  const int lane = threadIdx.x & 63;
  const int wave = threadIdx.x >> 6;
  const int bid  = blockIdx.x;

  if (bid < 256) {
    // ---------- xA: 16 rows/block, 4 rows/wave; 1 A-row per lane per iter ----------
    const int m0 = bid * 16 + wave * 4;
    float p[4][16];
#pragma unroll
    for (int a = 0; a < 4; ++a)
#pragma unroll
      for (int r = 0; r < 16; ++r) p[a][r] = 0.f;

    for (int k = lane; k < INF; k += 64) {
      const float4* a4 = (const float4*)&A[(size_t)k * RANKD];
      float av[16];
      *(float4*)&av[0]  = a4[0];
      *(float4*)&av[4]  = a4[1];
      *(float4*)&av[8]  = a4[2];
      *(float4*)&av[12] = a4[3];
#pragma unroll
      for (int rr = 0; rr < 4; ++rr) {
        const float xv = x[(size_t)(m0 + rr) * INF + k];
#pragma unroll
        for (int r = 0; r < 16; ++r) p[rr][r] = fmaf(xv, av[r], p[rr][r]);
      }
    }
#pragma unroll
    for (int rr = 0; rr < 4; ++rr)
#pragma unroll
      for (int r = 0; r < 16; ++r) {
        float v = p[rr][r];
        v += __shfl_xor(v, 1);
        v += __shfl_xor(v, 2);
        v += __shfl_xor(v, 4);
        v += __shfl_xor(v, 8);
        v += __shfl_xor(v, 16);
        v += __shfl_xor(v, 32);
        p[rr][r] = v;
      }
    const ushort8 z = {0, 0, 0, 0, 0, 0, 0, 0};
#pragma unroll
    for (int rr = 0; rr < 4; ++rr) {
      unsigned short* dst = Xe + (size_t)(m0 + rr) * KE + INF;
      if (lane == 0) {
        ushort8 v0, v1;
#pragma unroll
        for (int r = 0; r < 8; ++r) v0[r] = f2b(2.f * p[rr][r]);
#pragma unroll
        for (int r = 0; r < 8; ++r) v1[r] = f2b(2.f * p[rr][8 + r]);
        *(ushort8*)(dst + 0) = v0;
        *(ushort8*)(dst + 8) = v1;
      }
      if (lane < 6) *(ushort8*)(dst + 16 + lane * 8) = z;   // pad 4112..4159
    }
  } else if (bid < 1280) {
    // ---------- Xe main cols: 4 rows/block, 1 row/wave, pure streaming ----------
    const int m = (bid - 256) * 4 + wave;
#pragma unroll
    for (int it = 0; it < 8; ++it) {
      const int k0 = it * 512 + lane * 8;
      const float4 v0 = *(const float4*)&x[(size_t)m * INF + k0];
      const float4 v1 = *(const float4*)&x[(size_t)m * INF + k0 + 4];
      ushort8 w;
      w[0] = f2b(v0.x); w[1] = f2b(v0.y); w[2] = f2b(v0.z); w[3] = f2b(v0.w);
      w[4] = f2b(v1.x); w[5] = f2b(v1.y); w[6] = f2b(v1.z); w[7] = f2b(v1.w);
      *(ushort8*)&Xe[(size_t)m * KE + k0] = w;
    }
  } else {
    // ---------- We fill: 4 rows/block ----------
    __shared__ float cbs[16];
    if (threadIdx.x < 16) cbs[threadIdx.x] = cb[threadIdx.x];
    __syncthreads();
    const int o = (bid - 1280) * 4 + wave;
#pragma unroll
    for (int it = 0; it < 8; ++it) {
      const int k0 = it * 512 + lane * 8;
      const int4 q0 = *(const int4*)&q[(size_t)o * INF + k0];
      const int4 q1 = *(const int4*)&q[(size_t)o * INF + k0 + 4];
      const float am = absmax[(size_t)o * 64 + (k0 >> 6)];
      ushort8 w;
      w[0] = f2b(cbs[q0.x] * am); w[1] = f2b(cbs[q0.y] * am);
      w[2] = f2b(cbs[q0.z] * am); w[3] = f2b(cbs[q0.w] * am);
      w[4] = f2b(cbs[q1.x] * am); w[5] = f2b(cbs[q1.y] * am);
      w[6] = f2b(cbs[q1.z] * am); w[7] = f2b(cbs[q1.w] * am);
      *(ushort8*)&We[(size_t)o * KE + k0] = w;
    }
    unsigned short* dst = We + (size_t)o * KE + INF;
    dst[lane] = (lane < 16) ? f2b(B[(size_t)lane * OUTF + o]) : (unsigned short)0;
  }
}

// ---------------- kernel 2: out = Xe @ We^T + bias  (r4/r7 structure, verbatim) ----
// 256x256 tile, BK=32, 8 waves (2Mx4N), 4-deep LDS ring (128 KB).
// Derived-waits pipeline: per K-tile one vmcnt(4)+barrier; two 16-MFMA setprio
// clusters; ds_reads pipelined one phase ahead (no lgkmcnt(0) drains).
__global__ __launch_bounds__(512, 2) void k_gemm(const unsigned short* __restrict__ Xe,
                                                 const unsigned short* __restrict__ We,
                                                 const float* __restrict__ bias,
                                                 float* __restrict__ out) {
  extern __shared__ unsigned short LDS[];   // 4 bufs x (A 8KB + B 8KB) = 128 KB

  const int tid  = threadIdx.x;
  const int lane = tid & 63;
  const int wave = tid >> 6;        // 0..7
  const int waveM = wave >> 2;      // 0..1 -> rows [waveM*128, +128)
  const int waveN = wave & 3;       // 0..3 -> cols [waveN*64, +64)

  // XCD chunking: 256 wgs, 32 per XCD as 4 tile-rows x 8 tile-cols (bijective)
  const int wg   = blockIdx.x;
  const int xcd  = wg & 7;
  const int loc  = wg >> 3;                 // 0..31
  const int trB  = ((xcd & 3) * 4 + (loc >> 3)) * 256;
  const int tcB  = ((xcd >> 2) * 8 + (loc & 7)) * 256;

  // ---- staging constants (linear LDS dest, pre-swizzled global source) ----
  const int srow = lane >> 2;
  const int wpr  = ((lane & 3) * 8) ^ (((lane >> 3) & 3) << 3); // ushort offset
  const unsigned short* gA0 = Xe + (size_t)(trB +       wave * 16 + srow) * KE + wpr;
  const unsigned short* gA1 = Xe + (size_t)(trB + 128 + wave * 16 + srow) * KE + wpr;
  const unsigned short* gB0 = We + (size_t)(tcB +       wave * 16 + srow) * KE + wpr;
  const unsigned short* gB1 = We + (size_t)(tcB + 128 + wave * 16 + srow) * KE + wpr;
  const int dA0 = wave * 512;
  const int dA1 = 4096 + wave * 512;
  const int dB0 = 8192 + wave * 512;
  const int dB1 = 12288 + wave * 512;

  // ---- fragment-read constants (swizzled byte offsets) ----
  const int fr  = lane & 15;
  const int cbk = (lane >> 4) * 16;
  const int sw  = ((fr >> 1) & 3) << 4;
  const int aoff = (waveM * 128 + fr) * 64 + (cbk ^ sw);
  const int boff = 16384 + (waveN * 64 + fr) * 64 + (cbk ^ sw);

  f32x4 acc[8][4];
#pragma unroll
  for (int i = 0; i < 8; ++i)
#pragma unroll
    for (int j = 0; j < 4; ++j) acc[i][j] = f32x4{0.f, 0.f, 0.f, 0.f};

#define STAGE(t)                                                        \
  {                                                                     \
    const int sb_ = ((t) & 3) * 16384;                                  \
    const int k0_ = (t) * 32;                                           \
    gload_lds16(gA0 + k0_, LDS + sb_ + dA0);                            \
    gload_lds16(gA1 + k0_, LDS + sb_ + dA1);                            \
    gload_lds16(gB0 + k0_, LDS + sb_ + dB0);                            \
    gload_lds16(gB1 + k0_, LDS + sb_ + dB1);                            \
  }

  // prologue: stage tiles 0,1; wait tile 0; pre-read tile 0's first-phase frags
  STAGE(0)
  STAGE(1)
  asm volatile("s_waitcnt vmcnt(4)" ::: "memory");
  __builtin_amdgcn_s_barrier();
  __builtin_amdgcn_sched_barrier(0);

  bf16x8 aLo[4], aHi[4], b[4], aLoN[4], bN[4];
  {
    const char* base0 = (const char*)LDS;
#pragma unroll
    for (int i = 0; i < 4; ++i)
      aLo[i] = *(const bf16x8*)(base0 + aoff + i * 1024);
#pragma unroll
    for (int j = 0; j < 4; ++j)
      b[j] = *(const bf16x8*)(base0 + boff + j * 1024);
  }

  for (int T = 0; T < NT - 2; ++T) {
    const char* base  = (const char*)LDS + (T & 3) * 32768;
    const char* baseN = (const char*)LDS + ((T + 1) & 3) * 32768;

    // ---- P0: read a4-7(T); stage T+2; MFMA lo; vmcnt(4)+barrier ----
#pragma unroll
    for (int i = 0; i < 4; ++i)
      aHi[i] = *(const bf16x8*)(base + aoff + (4 + i) * 1024);
    STAGE(T + 2)
    __builtin_amdgcn_s_setprio(1);
#pragma unroll
    for (int i = 0; i < 4; ++i)
#pragma unroll
      for (int j = 0; j < 4; ++j)
        acc[i][j] = __builtin_amdgcn_mfma_f32_16x16x32_bf16(aLo[i], b[j], acc[i][j], 0, 0, 0);
    __builtin_amdgcn_s_setprio(0);
    asm volatile("s_waitcnt vmcnt(4)" ::: "memory");   // tile T+1 landed; T+2 in flight
    __builtin_amdgcn_s_barrier();
    __builtin_amdgcn_sched_barrier(0);

    // ---- P1: read a0-3,b0-3(T+1); MFMA hi ----
#pragma unroll
    for (int i = 0; i < 4; ++i)
      aLoN[i] = *(const bf16x8*)(baseN + aoff + i * 1024);
#pragma unroll
    for (int j = 0; j < 4; ++j)
      bN[j] = *(const bf16x8*)(baseN + boff + j * 1024);
    __builtin_amdgcn_s_setprio(1);
#pragma unroll
    for (int i = 0; i < 4; ++i)
#pragma unroll
      for (int j = 0; j < 4; ++j)
        acc[4 + i][j] = __builtin_amdgcn_mfma_f32_16x16x32_bf16(aHi[i], b[j], acc[4 + i][j], 0, 0, 0);
    __builtin_amdgcn_s_setprio(0);
#pragma unroll
    for (int i = 0; i < 4; ++i) aLo[i] = aLoN[i];
#pragma unroll
    for (int j = 0; j < 4; ++j) b[j] = bN[j];
  }

  // ---- peel T = NT-2: no stage; vmcnt(0) so tile NT-1 lands ----
  {
    const int T = NT - 2;
    const char* base  = (const char*)LDS + (T & 3) * 32768;
    const char* baseN = (const char*)LDS + ((T + 1) & 3) * 32768;
#pragma unroll
    for (int i = 0; i < 4; ++i)
      aHi[i] = *(const bf16x8*)(base + aoff + (4 + i) * 1024);
#pragma unroll
    for (int i = 0; i < 4; ++i)
#pragma unroll
      for (int j = 0; j < 4; ++j)
        acc[i][j] = __builtin_amdgcn_mfma_f32_16x16x32_bf16(aLo[i], b[j], acc[i][j], 0, 0, 0);
    asm volatile("s_waitcnt vmcnt(0)" ::: "memory");
    __builtin_amdgcn_s_barrier();
    __builtin_amdgcn_sched_barrier(0);
#pragma unroll
    for (int i = 0; i < 4; ++i)
      aLoN[i] = *(const bf16x8*)(baseN + aoff + i * 1024);
#pragma unroll
    for (int j = 0; j < 4; ++j)
      bN[j] = *(const bf16x8*)(baseN + boff + j * 1024);
#pragma unroll
    for (int i = 0; i < 4; ++i)
#pragma unroll
      for (int j = 0; j < 4; ++j)
        acc[4 + i][j] = __builtin_amdgcn_mfma_f32_16x16x32_bf16(aHi[i], b[j], acc[4 + i][j], 0, 0, 0);
#pragma unroll
    for (int i = 0; i < 4; ++i) aLo[i] = aLoN[i];
#pragma unroll
    for (int j = 0; j < 4; ++j) b[j] = bN[j];
  }
  // ---- peel T = NT-1: last tile, no next reads ----
  {
    const int T = NT - 1;
    const char* base = (const char*)LDS + (T & 3) * 32768;
#pragma unroll
    for (int i = 0; i < 4; ++i)
      aHi[i] = *(const bf16x8*)(base + aoff + (4 + i) * 1024);
#pragma unroll
    for (int i = 0; i < 4; ++i)
#pragma unroll
      for (int j = 0; j < 4; ++j)
        acc[i][j] = __builtin_amdgcn_mfma_f32_16x16x32_bf16(aLo[i], b[j], acc[i][j], 0, 0, 0);
#pragma unroll
    for (int i = 0; i < 4; ++i)
#pragma unroll
      for (int j = 0; j < 4; ++j)
        acc[4 + i][j] = __builtin_amdgcn_mfma_f32_16x16x32_bf16(aHi[i], b[j], acc[4 + i][j], 0, 0, 0);
  }
#undef STAGE

  // epilogue: C/D layout col = lane&15, row = (lane>>4)*4 + reg
  const int rq = (lane >> 4) * 4;
#pragma unroll
  for (int j = 0; j < 4; ++j) {
    const int n = tcB + waveN * 64 + j * 16 + fr;
    const float bsv = bias[n];
#pragma unroll
    for (int i = 0; i < 8; ++i) {
      const int m = trB + waveM * 128 + i * 16 + rq;
#pragma unroll
      for (int e = 0; e < 4; ++e)
        out[(size_t)(m + e) * OUTF + n] = acc[i][j][e] + bsv;
    }
  }
}

extern "C" void kernel_launch(void* const* d_in, const int* in_sizes, int n_in,
                              void* d_out, int out_size, void* d_ws, size_t ws_size,
                              hipStream_t stream) {
  const float* x      = (const float*)d_in[0];
  const int*   q      = (const int*)d_in[1];
  const float* absmax = (const float*)d_in[2];
  const float* cb     = (const float*)d_in[3];
  const float* bias   = (const float*)d_in[4];
  const float* A      = (const float*)d_in[5];
  const float* B      = (const float*)d_in[6];
  float* out = (float*)d_out;

  unsigned short* Xe = (unsigned short*)d_ws;              // 4096*4160*2 B
  unsigned short* We = Xe + (size_t)TOK * KE;              // 4096*4160*2 B

  hipFuncSetAttribute((const void*)k_gemm,
                      hipFuncAttributeMaxDynamicSharedMemorySize, 131072);

  k_prep<<<2304, 256, 0, stream>>>(x, A, q, absmax, cb, B, Xe, We);
  k_gemm<<<256, 512, 131072, stream>>>(Xe, We, bias, out);
}